// Round 2
// baseline (614.155 us; speedup 1.0000x reference)
//
#include <hip/hip_runtime.h>
#include <hip/hip_bf16.h>

typedef __attribute__((ext_vector_type(8))) short short8;
typedef __attribute__((ext_vector_type(4))) float f32x4;
typedef unsigned short ushort_t;

#define BM 128
#define BN 128
#define BK 64

__device__ __forceinline__ ushort_t f2bf_rne(float f) {
    unsigned u = __float_as_uint(f);
    u += 0x7FFF + ((u >> 16) & 1);   // round-to-nearest-even
    return (ushort_t)(u >> 16);
}

// One wave per row: sum 1000 int32 outcomes, scale by 1/(1000*15).
__global__ void expect_kernel(const int* __restrict__ q, float* __restrict__ e,
                              int rows, int shots) {
    int row = blockIdx.x * (blockDim.x >> 6) + (threadIdx.x >> 6);
    int lane = threadIdx.x & 63;
    if (row >= rows) return;
    const int* rp = q + (long long)row * shots;
    int s = 0;
    for (int j = lane; j < shots; j += 64) s += rp[j];
    #pragma unroll
    for (int off = 32; off; off >>= 1) s += __shfl_down(s, off, 64);
    if (lane == 0) e[row] = (float)s * (1.0f / (1000.0f * 15.0f));
}

// fp32 -> bf16 (RNE), 4 elements/thread.
__global__ void cvt_kernel(const float* __restrict__ src, ushort_t* __restrict__ dst,
                           long long n4) {
    long long i = (long long)blockIdx.x * blockDim.x + threadIdx.x;
    if (i >= n4) return;
    float4 v = ((const float4*)src)[i];
    ushort4 o;
    o.x = f2bf_rne(v.x); o.y = f2bf_rne(v.y);
    o.z = f2bf_rne(v.z); o.w = f2bf_rne(v.w);
    ((ushort4*)dst)[i] = o;
}

// ---------------------------------------------------------------------------
// Primary: NT-GEMM on pre-converted bf16 (m97 structure: 128x128 tile, BK=64,
// 4 waves 2x2, global_load_lds width=16, 16x16x32 bf16 MFMA, 4x4 acc/wave).
// C[m,n] = sum_k A[m,k]*B[n,k] + bias[n] + expect[m], fp32 out.
// ---------------------------------------------------------------------------
__global__ __launch_bounds__(256, 2)
void gemm_kernel(const ushort_t* __restrict__ A, const ushort_t* __restrict__ B,
                 const float* __restrict__ bias, const float* __restrict__ expect,
                 float* __restrict__ C, int M, int N, int K) {
    __shared__ ushort_t As[BM * BK];   // 16 KB, NO padding (global_load_lds)
    __shared__ ushort_t Bs[BN * BK];   // 16 KB

    const int num_pid_n = N / BN;
    const int GROUP = 8;
    int pid = blockIdx.x;
    int group_size = GROUP * num_pid_n;
    int gid = pid / group_size;
    int pin = pid - gid * group_size;
    int pid_m = gid * GROUP + (pin % GROUP);
    int pid_n = pin / GROUP;

    const int tid  = threadIdx.x;
    const int lane = tid & 63;
    const int wave = tid >> 6;
    const int wm = (wave >> 1) * 64;
    const int wn = (wave & 1) * 64;

    // staging: lds byte = tid*16 (wave-uniform base + lane*16) -- required form
    const int srow = tid >> 3;                 // 0..31
    const int scol = (tid & 7) * 8;            // element offset (8 bf16 = 16B)

    const ushort_t* a_ptr = A + (long long)pid_m * BM * K + scol;
    const ushort_t* b_ptr = B + (long long)pid_n * BN * K + scol;

    f32x4 acc[4][4];
    #pragma unroll
    for (int i = 0; i < 4; i++)
        #pragma unroll
        for (int j = 0; j < 4; j++)
            acc[i][j] = (f32x4)(0.0f);

    const int quad = lane >> 4;
    const int l15  = lane & 15;

    for (int k0 = 0; k0 < K; k0 += BK) {
        #pragma unroll
        for (int s = 0; s < 4; s++) {
            int row = srow + s * 32;
            __builtin_amdgcn_global_load_lds(
                (const __attribute__((address_space(1))) unsigned int*)(a_ptr + (long long)row * K + k0),
                (__attribute__((address_space(3))) unsigned int*)(As + row * BK + scol),
                16, 0, 0);
        }
        #pragma unroll
        for (int s = 0; s < 4; s++) {
            int row = srow + s * 32;
            __builtin_amdgcn_global_load_lds(
                (const __attribute__((address_space(1))) unsigned int*)(b_ptr + (long long)row * K + k0),
                (__attribute__((address_space(3))) unsigned int*)(Bs + row * BK + scol),
                16, 0, 0);
        }
        __syncthreads();

        #pragma unroll
        for (int ks = 0; ks < 2; ks++) {
            int ko = ks * 32 + quad * 8;
            short8 af[4], bf[4];
            #pragma unroll
            for (int i = 0; i < 4; i++) {
                af[i] = *(const short8*)(As + (wm + i * 16 + l15) * BK + ko);
                bf[i] = *(const short8*)(Bs + (wn + i * 16 + l15) * BK + ko);
            }
            #pragma unroll
            for (int i = 0; i < 4; i++)
                #pragma unroll
                for (int j = 0; j < 4; j++)
                    acc[i][j] = __builtin_amdgcn_mfma_f32_16x16x32_bf16(
                        af[i], bf[j], acc[i][j], 0, 0, 0);
        }
        __syncthreads();
    }

    // epilogue: C/D layout col = lane&15, row = quad*4 + reg  [m89-verified]
    long long row0 = (long long)pid_m * BM + wm;
    int col0 = pid_n * BN + wn;
    #pragma unroll
    for (int j = 0; j < 4; j++) {
        int col = col0 + j * 16 + l15;
        float bj = bias[col];
        #pragma unroll
        for (int i = 0; i < 4; i++) {
            #pragma unroll
            for (int r = 0; r < 4; r++) {
                long long row = row0 + i * 16 + quad * 4 + r;
                C[row * N + col] = acc[i][j][r] + bj + expect[row];
            }
        }
    }
}

// ---------------------------------------------------------------------------
// Fallback (small ws): same tile/MFMA structure, but stages fp32 from global
// through VGPRs with fp32->bf16 conversion into LDS (no global_load_lds).
// ---------------------------------------------------------------------------
__device__ __forceinline__ short8 pack8(float4 a, float4 b) {
    short8 r;
    r[0] = (short)f2bf_rne(a.x); r[1] = (short)f2bf_rne(a.y);
    r[2] = (short)f2bf_rne(a.z); r[3] = (short)f2bf_rne(a.w);
    r[4] = (short)f2bf_rne(b.x); r[5] = (short)f2bf_rne(b.y);
    r[6] = (short)f2bf_rne(b.z); r[7] = (short)f2bf_rne(b.w);
    return r;
}

__global__ __launch_bounds__(256, 2)
void gemm_f32stage_kernel(const float* __restrict__ A, const float* __restrict__ B,
                          const float* __restrict__ bias, const float* __restrict__ expect,
                          float* __restrict__ C, int M, int N, int K) {
    __shared__ ushort_t As[BM * BK];
    __shared__ ushort_t Bs[BN * BK];

    const int num_pid_n = N / BN;
    const int GROUP = 8;
    int pid = blockIdx.x;
    int group_size = GROUP * num_pid_n;
    int gid = pid / group_size;
    int pin = pid - gid * group_size;
    int pid_m = gid * GROUP + (pin % GROUP);
    int pid_n = pin / GROUP;

    const int tid  = threadIdx.x;
    const int lane = tid & 63;
    const int wave = tid >> 6;
    const int wm = (wave >> 1) * 64;
    const int wn = (wave & 1) * 64;

    // staging: thread covers row tid>>1, 32-col half (tid&1)
    const int srow = tid >> 1;                 // 0..127
    const int shalf = (tid & 1) * 32;          // 0 or 32 (fp32 elements)

    const float* a_base = A + ((long long)pid_m * BM + srow) * K + shalf;
    const float* b_base = B + ((long long)pid_n * BN + srow) * K + shalf;

    f32x4 acc[4][4];
    #pragma unroll
    for (int i = 0; i < 4; i++)
        #pragma unroll
        for (int j = 0; j < 4; j++)
            acc[i][j] = (f32x4)(0.0f);

    const int quad = lane >> 4;
    const int l15  = lane & 15;

    for (int k0 = 0; k0 < K; k0 += BK) {
        {
            const float4* ap = (const float4*)(a_base + k0);
            const float4* bp = (const float4*)(b_base + k0);
            float4 fa[8], fb[8];
            #pragma unroll
            for (int c = 0; c < 8; c++) { fa[c] = ap[c]; fb[c] = bp[c]; }
            #pragma unroll
            for (int c = 0; c < 4; c++) {
                *(short8*)(As + srow * BK + shalf + c * 8) = pack8(fa[2*c], fa[2*c+1]);
                *(short8*)(Bs + srow * BK + shalf + c * 8) = pack8(fb[2*c], fb[2*c+1]);
            }
        }
        __syncthreads();

        #pragma unroll
        for (int ks = 0; ks < 2; ks++) {
            int ko = ks * 32 + quad * 8;
            short8 af[4], bf[4];
            #pragma unroll
            for (int i = 0; i < 4; i++) {
                af[i] = *(const short8*)(As + (wm + i * 16 + l15) * BK + ko);
                bf[i] = *(const short8*)(Bs + (wn + i * 16 + l15) * BK + ko);
            }
            #pragma unroll
            for (int i = 0; i < 4; i++)
                #pragma unroll
                for (int j = 0; j < 4; j++)
                    acc[i][j] = __builtin_amdgcn_mfma_f32_16x16x32_bf16(
                        af[i], bf[j], acc[i][j], 0, 0, 0);
        }
        __syncthreads();
    }

    long long row0 = (long long)pid_m * BM + wm;
    int col0 = pid_n * BN + wn;
    #pragma unroll
    for (int j = 0; j < 4; j++) {
        int col = col0 + j * 16 + l15;
        float bj = bias[col];
        #pragma unroll
        for (int i = 0; i < 4; i++) {
            #pragma unroll
            for (int r = 0; r < 4; r++) {
                long long row = row0 + i * 16 + quad * 4 + r;
                C[row * N + col] = acc[i][j][r] + bj + expect[row];
            }
        }
    }
}

extern "C" void kernel_launch(void* const* d_in, const int* in_sizes, int n_in,
                              void* d_out, int out_size, void* d_ws, size_t ws_size,
                              hipStream_t stream) {
    const float* x = (const float*)d_in[0];   // [8192, 4096] fp32
    const float* W = (const float*)d_in[1];   // [4096, 4096] fp32
    const float* b = (const float*)d_in[2];   // [4096] fp32
    const int*   q = (const int*)d_in[3];     // [8192, 1000] int32
    float* out = (float*)d_out;               // [8192, 4096] fp32

    const int M = 8192, N = 4096, K = 4096, SHOTS = 1000;

    float* expect = (float*)d_ws;             // 32 KB
    size_t need = 32768 + (size_t)M * K * 2 + (size_t)N * K * 2;  // ~96 MB

    expect_kernel<<<M / 4, 256, 0, stream>>>(q, expect, M, SHOTS);

    if (ws_size >= need) {
        ushort_t* xb = (ushort_t*)((char*)d_ws + 32768);
        ushort_t* wb = xb + (size_t)M * K;
        cvt_kernel<<<(int)((long long)M * K / 4 / 256), 256, 0, stream>>>(x, xb, (long long)M * K / 4);
        cvt_kernel<<<(int)((long long)N * K / 4 / 256), 256, 0, stream>>>(W, wb, (long long)N * K / 4);
        gemm_kernel<<<(M / BM) * (N / BN), 256, 0, stream>>>(xb, wb, b, expect, out, M, N, K);
    } else {
        gemm_f32stage_kernel<<<(M / BM) * (N / BN), 256, 0, stream>>>(x, W, b, expect, out, M, N, K);
    }
}

// Round 4
// 589.779 us; speedup vs baseline: 1.0413x; 1.0413x over previous
//
#include <hip/hip_runtime.h>
#include <hip/hip_bf16.h>

typedef __attribute__((ext_vector_type(8))) short short8;
typedef __attribute__((ext_vector_type(4))) float f32x4;
typedef unsigned short ushort_t;

#define BM 128
#define BN 128
#define BK 64

__device__ __forceinline__ ushort_t f2bf_rne(float f) {
    unsigned u = __float_as_uint(f);
    u += 0x7FFF + ((u >> 16) & 1);   // round-to-nearest-even
    return (ushort_t)(u >> 16);
}

// One wave per row: sum 1000 int32 outcomes, scale by 1/(1000*15).
__global__ void expect_kernel(const int* __restrict__ q, float* __restrict__ e,
                              int rows, int shots) {
    int row = blockIdx.x * (blockDim.x >> 6) + (threadIdx.x >> 6);
    int lane = threadIdx.x & 63;
    if (row >= rows) return;
    const int* rp = q + (long long)row * shots;
    int s = 0;
    for (int j = lane; j < shots; j += 64) s += rp[j];
    #pragma unroll
    for (int off = 32; off; off >>= 1) s += __shfl_down(s, off, 64);
    if (lane == 0) e[row] = (float)s * (1.0f / (1000.0f * 15.0f));
}

__device__ __forceinline__ short8 pack8(float4 a, float4 b) {
    short8 r;
    r[0] = (short)f2bf_rne(a.x); r[1] = (short)f2bf_rne(a.y);
    r[2] = (short)f2bf_rne(a.z); r[3] = (short)f2bf_rne(a.w);
    r[4] = (short)f2bf_rne(b.x); r[5] = (short)f2bf_rne(b.y);
    r[6] = (short)f2bf_rne(b.z); r[7] = (short)f2bf_rne(b.w);
    return r;
}

// fp32 -> bf16 for BOTH x and W in one dispatch. 8 floats/thread:
// 32 B load, 16 B store per lane.
__global__ void cvt2_kernel(const float* __restrict__ x, ushort_t* __restrict__ xb,
                            const float* __restrict__ w, ushort_t* __restrict__ wb,
                            int blocks_x) {
    const float* src; ushort_t* dst; long long base;
    if (blockIdx.x < blocks_x) {
        src = x; dst = xb; base = (long long)blockIdx.x * blockDim.x;
    } else {
        src = w; dst = wb; base = (long long)(blockIdx.x - blocks_x) * blockDim.x;
    }
    long long i = base + threadIdx.x;        // chunk of 8 floats
    float4 a = ((const float4*)src)[2 * i];
    float4 b = ((const float4*)src)[2 * i + 1];
    ((short8*)dst)[i] = pack8(a, b);
}

// ---------------------------------------------------------------------------
// NT-GEMM on bf16 (m97 structure) + XOR-swizzled LDS layout.
// LDS(row, slot s) holds global chunk (s ^ (row&7)) of that row; reads of
// global chunk q use slot (q ^ (row&7)). Kills the row-stride-128B bank
// aliasing (all-quad-lanes-same-bank -> 2x ds_read slowdown, 1e8 conflicts).
// C[m,n] = sum_k A[m,k]*B[n,k] + bias[n] + expect[m], fp32 out.
// ---------------------------------------------------------------------------
__global__ __launch_bounds__(256, 2)
void gemm_kernel(const ushort_t* __restrict__ A, const ushort_t* __restrict__ B,
                 const float* __restrict__ bias, const float* __restrict__ expect,
                 float* __restrict__ C, int M, int N, int K) {
    __shared__ ushort_t As[BM * BK];   // 16 KB, NO padding (global_load_lds)
    __shared__ ushort_t Bs[BN * BK];   // 16 KB

    const int num_pid_n = N / BN;
    const int GROUP = 8;
    int pid = blockIdx.x;
    int group_size = GROUP * num_pid_n;
    int gid = pid / group_size;
    int pin = pid - gid * group_size;
    int pid_m = gid * GROUP + (pin % GROUP);
    int pid_n = pin / GROUP;

    const int tid  = threadIdx.x;
    const int lane = tid & 63;
    const int wave = tid >> 6;
    const int wm = (wave >> 1) * 64;
    const int wn = (wave & 1) * 64;

    // staging: LDS dest byte = tid*16 (wave-uniform base + lane*16 -- required
    // form). slot = tid&7; the GLOBAL chunk fetched is swizzled by row.
    const int srow = tid >> 3;                      // 0..31
    const int slot = tid & 7;                       // LDS 16B slot in row
    const int gchunk = slot ^ (srow & 7);           // global 16B chunk
    // rows srow + s*32 share (row&7) == (srow&7), so gchunk is loop-invariant

    const ushort_t* a_ptr = A + (long long)pid_m * BM * K + gchunk * 8;
    const ushort_t* b_ptr = B + (long long)pid_n * BN * K + gchunk * 8;

    f32x4 acc[4][4];
    #pragma unroll
    for (int i = 0; i < 4; i++)
        #pragma unroll
        for (int j = 0; j < 4; j++)
            acc[i][j] = (f32x4)(0.0f);

    const int quad = lane >> 4;
    const int l15  = lane & 15;
    const int rlow = l15 & 7;                       // row low bits on read side

    for (int k0 = 0; k0 < K; k0 += BK) {
        #pragma unroll
        for (int s = 0; s < 4; s++) {
            int row = srow + s * 32;
            __builtin_amdgcn_global_load_lds(
                (const __attribute__((address_space(1))) unsigned int*)(a_ptr + (long long)row * K + k0),
                (__attribute__((address_space(3))) unsigned int*)(As + row * BK + slot * 8),
                16, 0, 0);
        }
        #pragma unroll
        for (int s = 0; s < 4; s++) {
            int row = srow + s * 32;
            __builtin_amdgcn_global_load_lds(
                (const __attribute__((address_space(1))) unsigned int*)(b_ptr + (long long)row * K + k0),
                (__attribute__((address_space(3))) unsigned int*)(Bs + row * BK + slot * 8),
                16, 0, 0);
        }
        __syncthreads();

        #pragma unroll
        for (int ks = 0; ks < 2; ks++) {
            int q = ks * 4 + quad;                  // global chunk index
            int sw = (q ^ rlow) * 8;                // swizzled LDS offset
            short8 af[4], bf[4];
            #pragma unroll
            for (int i = 0; i < 4; i++) {
                af[i] = *(const short8*)(As + (wm + i * 16 + l15) * BK + sw);
                bf[i] = *(const short8*)(Bs + (wn + i * 16 + l15) * BK + sw);
            }
            #pragma unroll
            for (int i = 0; i < 4; i++)
                #pragma unroll
                for (int j = 0; j < 4; j++)
                    acc[i][j] = __builtin_amdgcn_mfma_f32_16x16x32_bf16(
                        af[i], bf[j], acc[i][j], 0, 0, 0);
        }
        __syncthreads();
    }

    // epilogue: C/D layout col = lane&15, row = quad*4 + reg  [m89-verified]
    long long row0 = (long long)pid_m * BM + wm;
    int col0 = pid_n * BN + wn;
    #pragma unroll
    for (int j = 0; j < 4; j++) {
        int col = col0 + j * 16 + l15;
        float bj = bias[col];
        #pragma unroll
        for (int i = 0; i < 4; i++) {
            #pragma unroll
            for (int r = 0; r < 4; r++) {
                long long row = row0 + i * 16 + quad * 4 + r;
                C[row * N + col] = acc[i][j][r] + bj + expect[row];
            }
        }
    }
}

// ---------------------------------------------------------------------------
// Fallback (small ws): same structure, stages fp32 through VGPRs with
// conversion into (swizzled) LDS. Only used if ws can't hold bf16 copies.
// ---------------------------------------------------------------------------
__global__ __launch_bounds__(256, 2)
void gemm_f32stage_kernel(const float* __restrict__ A, const float* __restrict__ B,
                          const float* __restrict__ bias, const float* __restrict__ expect,
                          float* __restrict__ C, int M, int N, int K) {
    __shared__ ushort_t As[BM * BK];
    __shared__ ushort_t Bs[BN * BK];

    const int num_pid_n = N / BN;
    const int GROUP = 8;
    int pid = blockIdx.x;
    int group_size = GROUP * num_pid_n;
    int gid = pid / group_size;
    int pin = pid - gid * group_size;
    int pid_m = gid * GROUP + (pin % GROUP);
    int pid_n = pin / GROUP;

    const int tid  = threadIdx.x;
    const int lane = tid & 63;
    const int wave = tid >> 6;
    const int wm = (wave >> 1) * 64;
    const int wn = (wave & 1) * 64;

    const int srow = tid >> 1;                 // 0..127
    const int chalf = (tid & 1) * 4;           // first chunk (of 8) this thread writes

    const float* a_base = A + ((long long)pid_m * BM + srow) * K + chalf * 8;
    const float* b_base = B + ((long long)pid_n * BN + srow) * K + chalf * 8;

    f32x4 acc[4][4];
    #pragma unroll
    for (int i = 0; i < 4; i++)
        #pragma unroll
        for (int j = 0; j < 4; j++)
            acc[i][j] = (f32x4)(0.0f);

    const int quad = lane >> 4;
    const int l15  = lane & 15;
    const int rlow = l15 & 7;

    for (int k0 = 0; k0 < K; k0 += BK) {
        {
            const float4* ap = (const float4*)(a_base + k0);
            const float4* bp = (const float4*)(b_base + k0);
            float4 fa[8], fb[8];
            #pragma unroll
            for (int c = 0; c < 8; c++) { fa[c] = ap[c]; fb[c] = bp[c]; }
            #pragma unroll
            for (int c = 0; c < 4; c++) {
                int sl = ((chalf + c) ^ (srow & 7)) * 8;   // swizzled slot
                *(short8*)(As + srow * BK + sl) = pack8(fa[2*c], fa[2*c+1]);
                *(short8*)(Bs + srow * BK + sl) = pack8(fb[2*c], fb[2*c+1]);
            }
        }
        __syncthreads();

        #pragma unroll
        for (int ks = 0; ks < 2; ks++) {
            int q = ks * 4 + quad;
            int sw = (q ^ rlow) * 8;
            short8 af[4], bf[4];
            #pragma unroll
            for (int i = 0; i < 4; i++) {
                af[i] = *(const short8*)(As + (wm + i * 16 + l15) * BK + sw);
                bf[i] = *(const short8*)(Bs + (wn + i * 16 + l15) * BK + sw);
            }
            #pragma unroll
            for (int i = 0; i < 4; i++)
                #pragma unroll
                for (int j = 0; j < 4; j++)
                    acc[i][j] = __builtin_amdgcn_mfma_f32_16x16x32_bf16(
                        af[i], bf[j], acc[i][j], 0, 0, 0);
        }
        __syncthreads();
    }

    long long row0 = (long long)pid_m * BM + wm;
    int col0 = pid_n * BN + wn;
    #pragma unroll
    for (int j = 0; j < 4; j++) {
        int col = col0 + j * 16 + l15;
        float bj = bias[col];
        #pragma unroll
        for (int i = 0; i < 4; i++) {
            #pragma unroll
            for (int r = 0; r < 4; r++) {
                long long row = row0 + i * 16 + quad * 4 + r;
                C[row * N + col] = acc[i][j][r] + bj + expect[row];
            }
        }
    }
}

extern "C" void kernel_launch(void* const* d_in, const int* in_sizes, int n_in,
                              void* d_out, int out_size, void* d_ws, size_t ws_size,
                              hipStream_t stream) {
    const float* x = (const float*)d_in[0];   // [8192, 4096] fp32
    const float* W = (const float*)d_in[1];   // [4096, 4096] fp32
    const float* b = (const float*)d_in[2];   // [4096] fp32
    const int*   q = (const int*)d_in[3];     // [8192, 1000] int32
    float* out = (float*)d_out;               // [8192, 4096] fp32

    const int M = 8192, N = 4096, K = 4096, SHOTS = 1000;

    float* expect = (float*)d_ws;             // 32 KB
    size_t need = 32768 + (size_t)M * K * 2 + (size_t)N * K * 2;  // ~96 MB

    expect_kernel<<<M / 4, 256, 0, stream>>>(q, expect, M, SHOTS);

    if (ws_size >= need) {
        ushort_t* xb = (ushort_t*)((char*)d_ws + 32768);
        ushort_t* wb = xb + (size_t)M * K;
        int blocks_x = (int)((long long)M * K / 8 / 256);   // 16384
        int blocks_w = (int)((long long)N * K / 8 / 256);   // 8192
        cvt2_kernel<<<blocks_x + blocks_w, 256, 0, stream>>>(x, xb, W, wb, blocks_x);
        gemm_kernel<<<(M / BM) * (N / BN), 256, 0, stream>>>(xb, wb, b, expect, out, M, N, K);
    } else {
        gemm_f32stage_kernel<<<(M / BM) * (N / BN), 256, 0, stream>>>(x, W, b, expect, out, M, N, K);
    }
}

// Round 5
// 549.783 us; speedup vs baseline: 1.1171x; 1.0727x over previous
//
#include <hip/hip_runtime.h>
#include <hip/hip_bf16.h>

typedef __attribute__((ext_vector_type(8))) short short8;
typedef __attribute__((ext_vector_type(4))) float f32x4;
typedef unsigned short ushort_t;

#define BM 128
#define BN 128
#define BK 64

__device__ __forceinline__ ushort_t f2bf_rne(float f) {
    unsigned u = __float_as_uint(f);
    u += 0x7FFF + ((u >> 16) & 1);   // round-to-nearest-even
    return (ushort_t)(u >> 16);
}

__device__ __forceinline__ short8 pack8(float4 a, float4 b) {
    short8 r;
    r[0] = (short)f2bf_rne(a.x); r[1] = (short)f2bf_rne(a.y);
    r[2] = (short)f2bf_rne(a.z); r[3] = (short)f2bf_rne(a.w);
    r[4] = (short)f2bf_rne(b.x); r[5] = (short)f2bf_rne(b.y);
    r[6] = (short)f2bf_rne(b.z); r[7] = (short)f2bf_rne(b.w);
    return r;
}

// Fused prep: fp32->bf16 for x and W (16 floats/thread: 64B load, 32B store)
// + per-row expectation of quantum outcomes, in one dispatch.
__global__ void prep_kernel(const float* __restrict__ x, ushort_t* __restrict__ xb,
                            const float* __restrict__ w, ushort_t* __restrict__ wb,
                            const int* __restrict__ q, float* __restrict__ e,
                            int blocks_x, int blocks_w, int shots) {
    int bid = blockIdx.x;
    if (bid < blocks_x + blocks_w) {
        const float* src; ushort_t* dst; long long base;
        if (bid < blocks_x) { src = x; dst = xb; base = (long long)bid * blockDim.x; }
        else { src = w; dst = wb; base = (long long)(bid - blocks_x) * blockDim.x; }
        long long i = base + threadIdx.x;      // chunk of 16 floats
        float4 a0 = ((const float4*)src)[4 * i];
        float4 a1 = ((const float4*)src)[4 * i + 1];
        float4 a2 = ((const float4*)src)[4 * i + 2];
        float4 a3 = ((const float4*)src)[4 * i + 3];
        ((short8*)dst)[2 * i]     = pack8(a0, a1);
        ((short8*)dst)[2 * i + 1] = pack8(a2, a3);
    } else {
        // expectation: one wave per row, 4 rows/block
        int eb = bid - (blocks_x + blocks_w);
        int row = eb * 4 + (threadIdx.x >> 6);
        int lane = threadIdx.x & 63;
        const int* rp = q + (long long)row * shots;
        int s = 0;
        for (int j = lane; j < shots; j += 64) s += rp[j];
        #pragma unroll
        for (int off = 32; off; off >>= 1) s += __shfl_down(s, off, 64);
        if (lane == 0) e[row] = (float)s * (1.0f / (1000.0f * 15.0f));
    }
}

// ---------------------------------------------------------------------------
// NT-GEMM on bf16, m97 structure + XOR-swizzled LDS (round-4: conflicts = 0)
// + XCD-aware block mapping: blocks dispatch round-robin over 8 XCDs
// (xcd = pid&7); XCD x owns N-blocks [4x,4x+4) -> its 4 MB B-strip lives in
// that XCD's private L2 for the whole kernel; A streams with 4x immediate
// reuse. Cuts the 8.8x FETCH over-fetch -> shorter global_load_lds drain.
// C[m,n] = sum_k A[m,k]*B[n,k] + bias[n] + expect[m], fp32 out.
// ---------------------------------------------------------------------------
__global__ __launch_bounds__(256, 2)
void gemm_kernel(const ushort_t* __restrict__ A, const ushort_t* __restrict__ B,
                 const float* __restrict__ bias, const float* __restrict__ expect,
                 float* __restrict__ C, int M, int N, int K) {
    __shared__ ushort_t As[BM * BK];   // 16 KB, NO padding (global_load_lds)
    __shared__ ushort_t Bs[BN * BK];   // 16 KB

    // XCD-aware mapping: N/BN = 32 = 8 XCDs * 4 strips; M/BM = 64.
    int pid = blockIdx.x;
    const int xcd = pid & 7;
    const int p   = pid >> 3;            // 0..255 per XCD
    int pid_n = xcd * 4 + (p & 3);       // 4-N-block strip owned by this XCD
    int pid_m = p >> 2;                  // sweeps M; A-strip reused 4x in a row

    const int tid  = threadIdx.x;
    const int lane = tid & 63;
    const int wave = tid >> 6;
    const int wm = (wave >> 1) * 64;
    const int wn = (wave & 1) * 64;

    // staging: LDS dest byte = tid*16 (wave-uniform base + lane*16 -- required
    // form). slot = tid&7; the GLOBAL chunk fetched is swizzled by row.
    const int srow = tid >> 3;                      // 0..31
    const int slot = tid & 7;                       // LDS 16B slot in row
    const int gchunk = slot ^ (srow & 7);           // global 16B chunk

    const ushort_t* a_ptr = A + (long long)pid_m * BM * K + gchunk * 8;
    const ushort_t* b_ptr = B + (long long)pid_n * BN * K + gchunk * 8;

    f32x4 acc[4][4];
    #pragma unroll
    for (int i = 0; i < 4; i++)
        #pragma unroll
        for (int j = 0; j < 4; j++)
            acc[i][j] = (f32x4)(0.0f);

    const int quad = lane >> 4;
    const int l15  = lane & 15;
    const int rlow = l15 & 7;                       // row low bits on read side

    for (int k0 = 0; k0 < K; k0 += BK) {
        #pragma unroll
        for (int s = 0; s < 4; s++) {
            int row = srow + s * 32;
            __builtin_amdgcn_global_load_lds(
                (const __attribute__((address_space(1))) unsigned int*)(a_ptr + (long long)row * K + k0),
                (__attribute__((address_space(3))) unsigned int*)(As + row * BK + slot * 8),
                16, 0, 0);
        }
        #pragma unroll
        for (int s = 0; s < 4; s++) {
            int row = srow + s * 32;
            __builtin_amdgcn_global_load_lds(
                (const __attribute__((address_space(1))) unsigned int*)(b_ptr + (long long)row * K + k0),
                (__attribute__((address_space(3))) unsigned int*)(Bs + row * BK + slot * 8),
                16, 0, 0);
        }
        __syncthreads();

        #pragma unroll
        for (int ks = 0; ks < 2; ks++) {
            int q = ks * 4 + quad;                  // global chunk index
            int sw = (q ^ rlow) * 8;                // swizzled LDS offset
            short8 af[4], bf[4];
            #pragma unroll
            for (int i = 0; i < 4; i++) {
                af[i] = *(const short8*)(As + (wm + i * 16 + l15) * BK + sw);
                bf[i] = *(const short8*)(Bs + (wn + i * 16 + l15) * BK + sw);
            }
            #pragma unroll
            for (int i = 0; i < 4; i++)
                #pragma unroll
                for (int j = 0; j < 4; j++)
                    acc[i][j] = __builtin_amdgcn_mfma_f32_16x16x32_bf16(
                        af[i], bf[j], acc[i][j], 0, 0, 0);
        }
        __syncthreads();
    }

    // epilogue: C/D layout col = lane&15, row = quad*4 + reg  [m89-verified]
    long long row0 = (long long)pid_m * BM + wm;
    int col0 = pid_n * BN + wn;
    #pragma unroll
    for (int j = 0; j < 4; j++) {
        int col = col0 + j * 16 + l15;
        float bj = bias[col];
        #pragma unroll
        for (int i = 0; i < 4; i++) {
            #pragma unroll
            for (int r = 0; r < 4; r++) {
                long long row = row0 + i * 16 + quad * 4 + r;
                C[row * N + col] = acc[i][j][r] + bj + expect[row];
            }
        }
    }
}

// ---------------------------------------------------------------------------
// Fallback (small ws): stages fp32 through VGPRs with conversion into
// (swizzled) LDS. Only used if ws can't hold the bf16 copies.
// ---------------------------------------------------------------------------
__global__ void expect_kernel(const int* __restrict__ q, float* __restrict__ e,
                              int rows, int shots) {
    int row = blockIdx.x * (blockDim.x >> 6) + (threadIdx.x >> 6);
    int lane = threadIdx.x & 63;
    if (row >= rows) return;
    const int* rp = q + (long long)row * shots;
    int s = 0;
    for (int j = lane; j < shots; j += 64) s += rp[j];
    #pragma unroll
    for (int off = 32; off; off >>= 1) s += __shfl_down(s, off, 64);
    if (lane == 0) e[row] = (float)s * (1.0f / (1000.0f * 15.0f));
}

__global__ __launch_bounds__(256, 2)
void gemm_f32stage_kernel(const float* __restrict__ A, const float* __restrict__ B,
                          const float* __restrict__ bias, const float* __restrict__ expect,
                          float* __restrict__ C, int M, int N, int K) {
    __shared__ ushort_t As[BM * BK];
    __shared__ ushort_t Bs[BN * BK];

    int pid = blockIdx.x;
    const int xcd = pid & 7;
    const int p   = pid >> 3;
    int pid_n = xcd * 4 + (p & 3);
    int pid_m = p >> 2;

    const int tid  = threadIdx.x;
    const int lane = tid & 63;
    const int wave = tid >> 6;
    const int wm = (wave >> 1) * 64;
    const int wn = (wave & 1) * 64;

    const int srow = tid >> 1;                 // 0..127
    const int chalf = (tid & 1) * 4;           // first chunk (of 8) this thread writes

    const float* a_base = A + ((long long)pid_m * BM + srow) * K + chalf * 8;
    const float* b_base = B + ((long long)pid_n * BN + srow) * K + chalf * 8;

    f32x4 acc[4][4];
    #pragma unroll
    for (int i = 0; i < 4; i++)
        #pragma unroll
        for (int j = 0; j < 4; j++)
            acc[i][j] = (f32x4)(0.0f);

    const int quad = lane >> 4;
    const int l15  = lane & 15;
    const int rlow = l15 & 7;

    for (int k0 = 0; k0 < K; k0 += BK) {
        {
            const float4* ap = (const float4*)(a_base + k0);
            const float4* bp = (const float4*)(b_base + k0);
            float4 fa[8], fb[8];
            #pragma unroll
            for (int c = 0; c < 8; c++) { fa[c] = ap[c]; fb[c] = bp[c]; }
            #pragma unroll
            for (int c = 0; c < 4; c++) {
                int sl = ((chalf + c) ^ (srow & 7)) * 8;   // swizzled slot
                *(short8*)(As + srow * BK + sl) = pack8(fa[2*c], fa[2*c+1]);
                *(short8*)(Bs + srow * BK + sl) = pack8(fb[2*c], fb[2*c+1]);
            }
        }
        __syncthreads();

        #pragma unroll
        for (int ks = 0; ks < 2; ks++) {
            int q = ks * 4 + quad;
            int sw = (q ^ rlow) * 8;
            short8 af[4], bf[4];
            #pragma unroll
            for (int i = 0; i < 4; i++) {
                af[i] = *(const short8*)(As + (wm + i * 16 + l15) * BK + sw);
                bf[i] = *(const short8*)(Bs + (wn + i * 16 + l15) * BK + sw);
            }
            #pragma unroll
            for (int i = 0; i < 4; i++)
                #pragma unroll
                for (int j = 0; j < 4; j++)
                    acc[i][j] = __builtin_amdgcn_mfma_f32_16x16x32_bf16(
                        af[i], bf[j], acc[i][j], 0, 0, 0);
        }
        __syncthreads();
    }

    long long row0 = (long long)pid_m * BM + wm;
    int col0 = pid_n * BN + wn;
    #pragma unroll
    for (int j = 0; j < 4; j++) {
        int col = col0 + j * 16 + l15;
        float bj = bias[col];
        #pragma unroll
        for (int i = 0; i < 4; i++) {
            #pragma unroll
            for (int r = 0; r < 4; r++) {
                long long row = row0 + i * 16 + quad * 4 + r;
                C[row * N + col] = acc[i][j][r] + bj + expect[row];
            }
        }
    }
}

extern "C" void kernel_launch(void* const* d_in, const int* in_sizes, int n_in,
                              void* d_out, int out_size, void* d_ws, size_t ws_size,
                              hipStream_t stream) {
    const float* x = (const float*)d_in[0];   // [8192, 4096] fp32
    const float* W = (const float*)d_in[1];   // [4096, 4096] fp32
    const float* b = (const float*)d_in[2];   // [4096] fp32
    const int*   q = (const int*)d_in[3];     // [8192, 1000] int32
    float* out = (float*)d_out;               // [8192, 4096] fp32

    const int M = 8192, N = 4096, K = 4096, SHOTS = 1000;

    float* expect = (float*)d_ws;             // 32 KB
    size_t need = 32768 + (size_t)M * K * 2 + (size_t)N * K * 2;  // ~96 MB

    if (ws_size >= need) {
        ushort_t* xb = (ushort_t*)((char*)d_ws + 32768);
        ushort_t* wb = xb + (size_t)M * K;
        int blocks_x = (int)((long long)M * K / 16 / 256);   // 8192
        int blocks_w = (int)((long long)N * K / 16 / 256);   // 4096
        int blocks_e = M / 4;                                // 2048
        prep_kernel<<<blocks_x + blocks_w + blocks_e, 256, 0, stream>>>(
            x, xb, W, wb, q, expect, blocks_x, blocks_w, SHOTS);
        gemm_kernel<<<(M / BM) * (N / BN), 256, 0, stream>>>(xb, wb, b, expect, out, M, N, K);
    } else {
        expect_kernel<<<M / 4, 256, 0, stream>>>(q, expect, M, SHOTS);
        gemm_f32stage_kernel<<<(M / BM) * (N / BN), 256, 0, stream>>>(x, W, b, expect, out, M, N, K);
    }
}